// Round 9
// baseline (34.256 us; speedup 1.0000x reference)
//
#include <hip/hip_runtime.h>
#include <math.h>
#include <float.h>

#define B_ 32
#define N_ 256
#define T_OBS_ 50
#define T_S_ 25
#define D_ 128
#define D_H_ 256
#define P_ 8
#define PLANE_ (T_S_ * D_)  // 3200 floats per (b,n)
#define TG_ 13              // t-pair groups per batch (12 pairs + clamped last)

static constexpr float TWO_PI_F = 6.2831854820251465f;      // float(2*pi)
static constexpr float BIN_W_F = 0.78539818525314331f;      // float32(2*pi/8)
static constexpr float EPS_F = 1e-4f;

// ---------------------------------------------------------------------------
// Single fused kernel, dependency-free: block = (batch b, t-pair g).
// Phase A: stream f_nei[b, :, {t0,t1}, :] (1 KB contiguous per wave-load,
//          L3-resident), max-reduce over n via 8 n-groups + LDS combine.
// Phase B: float4 RB2 MLP + per-wave histogram (float32 math, replicating
//          the reference's float32 binning exactly) + output.
// 416 blocks x 512 threads.
// ---------------------------------------------------------------------------
__global__ __launch_bounds__(512) void fused(
    const float* __restrict__ f_ego, const float* __restrict__ f_nei,
    const float* __restrict__ W1, const float* __restrict__ b1,
    const float* __restrict__ W2, const float* __restrict__ b2,
    const float* __restrict__ W3, const float* __restrict__ b3,
    const float* __restrict__ x_ego, const float* __restrict__ x_nei,
    const float* __restrict__ Wce, const float* __restrict__ bce,
    float* __restrict__ out) {
  __shared__ float spool[4096];   // 16 KB: n-max partials, then k-slice pool
  __shared__ float sin_[2][D_];   // 1 KB
  __shared__ float sh1[2][D_H_];  // 2 KB
  __shared__ float sh2[2][D_H_];  // 2 KB
  __shared__ float f3s[2][64];
  __shared__ float whc[8][P_], whd[8][P_], wha[8][P_];  // per-wave hist
  __shared__ float cnt[2][P_], dsum[2][P_], asum[2][P_];

  const int tid = threadIdx.x;
  const int b = blockIdx.x / TG_;
  const int g = blockIdx.x - b * TG_;
  const int t0 = 2 * g;
  const int t1 = (2 * g + 1 < T_S_) ? (2 * g + 1) : (T_S_ - 1);

  // zero per-wave histograms (ordered before atomics by barriers below)
  if (tid < 8 * P_) {
    (&whc[0][0])[tid] = 0.f;
    (&whd[0][0])[tid] = 0.f;
    (&wha[0][0])[tid] = 0.f;
  }

  // ---- phase A: stream & partial-max. thread = (ng = tid>>6, sub = tid&63);
  //      sub -> (lt = sub>>5, d4 = sub&31); n = ng + 8*i, i = 0..31 ----
  {
    const int sub = tid & 63;
    const int lt = sub >> 5;
    const int d4 = sub & 31;
    const int ng = tid >> 6;
    const int t = lt ? t1 : t0;
    const float4 e =
        *(const float4*)(f_ego + ((size_t)b * T_S_ + t) * D_ + 4 * d4);
    const float* base = f_nei + (size_t)b * N_ * PLANE_ + t * D_ + 4 * d4;
    float4 m = make_float4(-FLT_MAX, -FLT_MAX, -FLT_MAX, -FLT_MAX);
#pragma unroll 16
    for (int i = 0; i < 32; ++i) {
      int n = ng + 8 * i;
      float4 v = *(const float4*)(base + (size_t)n * PLANE_);
      m.x = fmaxf(m.x, e.x * v.x);
      m.y = fmaxf(m.y, e.y * v.y);
      m.z = fmaxf(m.z, e.z * v.z);
      m.w = fmaxf(m.w, e.w * v.w);
    }
    ((float4*)spool)[ng * 64 + sub] = m;  // part[ng][sub]
  }

  // ---- histogram input loads (independent; hide under combine) ----
  float2 eg, xn;
  {
    int r = tid >> 8, n = tid & 255;
    int t = r ? t1 : t0;
    int tobs = 2 * t;
    eg = *(const float2*)&x_ego[((size_t)b * T_OBS_ + tobs) * 2];
    xn = *(const float2*)&x_nei[(((size_t)b * N_ + n) * T_OBS_ + tobs) * 2];
  }
  const float bb1 = b1[tid & 255];
  const float bb2 = b2[tid & 255];

  __syncthreads();  // A-parts complete

  // ---- combine 8 n-group partials -> sin_ (64 threads, 1 float4 each) ----
  if (tid < 64) {
    float4 r = ((float4*)spool)[tid];
#pragma unroll
    for (int ngg = 1; ngg < 8; ++ngg) {
      float4 v = ((float4*)spool)[ngg * 64 + tid];
      r.x = fmaxf(r.x, v.x);
      r.y = fmaxf(r.y, v.y);
      r.z = fmaxf(r.z, v.z);
      r.w = fmaxf(r.w, v.w);
    }
    *(float4*)&sin_[tid >> 5][4 * (tid & 31)] = r;
  }
  __syncthreads();  // B1: sin_ ready, spool free

  // ---- layer 1: 128 -> 256. s=tid>>6 (8 slices of 16 k), j4=tid&63 ----
  {
    const int s = tid >> 6, j4 = tid & 63;
    const float4* W1v = (const float4*)W1;
    float a[2][4] = {};
#pragma unroll
    for (int kk = 0; kk < 16; ++kk) {
      int k = s * 16 + kk;
      float4 w = W1v[k * 64 + j4];
#pragma unroll
      for (int r = 0; r < 2; ++r) {
        float x = sin_[r][k];
        a[r][0] = fmaf(x, w.x, a[r][0]);
        a[r][1] = fmaf(x, w.y, a[r][1]);
        a[r][2] = fmaf(x, w.z, a[r][2]);
        a[r][3] = fmaf(x, w.w, a[r][3]);
      }
    }
#pragma unroll
    for (int r = 0; r < 2; ++r)
      *(float4*)&spool[(s * 2 + r) * 256 + 4 * j4] =
          make_float4(a[r][0], a[r][1], a[r][2], a[r][3]);
  }
  __syncthreads();  // B2
  {
    int r = tid >> 8, j = tid & 255;
    float sum = bb1;
#pragma unroll
    for (int s = 0; s < 8; ++s) sum += spool[(s * 2 + r) * 256 + j];
    sh1[r][j] = fmaxf(sum, 0.f);
  }
  __syncthreads();  // B3: sh1 ready

  // ---- layer 2: 256 -> 256. 8 slices of 32 k ----
  {
    const int s = tid >> 6, j4 = tid & 63;
    const float4* W2v = (const float4*)W2;
    float a[2][4] = {};
#pragma unroll
    for (int kk = 0; kk < 32; ++kk) {
      int k = s * 32 + kk;
      float4 w = W2v[k * 64 + j4];
#pragma unroll
      for (int r = 0; r < 2; ++r) {
        float x = sh1[r][k];
        a[r][0] = fmaf(x, w.x, a[r][0]);
        a[r][1] = fmaf(x, w.y, a[r][1]);
        a[r][2] = fmaf(x, w.z, a[r][2]);
        a[r][3] = fmaf(x, w.w, a[r][3]);
      }
    }
#pragma unroll
    for (int r = 0; r < 2; ++r)
      *(float4*)&spool[(s * 2 + r) * 256 + 4 * j4] =
          make_float4(a[r][0], a[r][1], a[r][2], a[r][3]);
  }
  __syncthreads();  // B4
  {
    int r = tid >> 8, j = tid & 255;
    float sum = bb2;
#pragma unroll
    for (int s = 0; s < 8; ++s) sum += spool[(s * 2 + r) * 256 + j];
    sh2[r][j] = fmaxf(sum, 0.f);
  }
  __syncthreads();  // B5: sh2 ready, spool free

  // ---- layer 3: 256 -> 64. s3=tid>>4 (32 slices of 8 k), j4=tid&15;
  //      plus histogram math + per-wave LDS atomics (independent) ----
  {
    const int s3 = tid >> 4, j4 = tid & 15;
    const float4* W3v = (const float4*)W3;
    float a[2][4] = {};
#pragma unroll
    for (int kk = 0; kk < 8; ++kk) {
      int k = s3 * 8 + kk;
      float4 w = W3v[k * 16 + j4];
#pragma unroll
      for (int r = 0; r < 2; ++r) {
        float x = sh2[r][k];
        a[r][0] = fmaf(x, w.x, a[r][0]);
        a[r][1] = fmaf(x, w.y, a[r][1]);
        a[r][2] = fmaf(x, w.z, a[r][2]);
        a[r][3] = fmaf(x, w.w, a[r][3]);
      }
    }
#pragma unroll
    for (int r = 0; r < 2; ++r)
      *(float4*)&spool[(s3 * 2 + r) * 64 + 4 * j4] =
          make_float4(a[r][0], a[r][1], a[r][2], a[r][3]);
  }
  {
    // float32 math replicating the reference exactly:
    // ang = atan2f(p0,p1); mod via +float(2pi); bin = trunc(ang / f32(2pi/8))
    const int w = tid >> 6;  // wave id 0..7 (waves 0-3: row 0, 4-7: row 1)
    float p0 = xn.x - eg.x;
    float p1 = xn.y - eg.y;
    float dist = sqrtf(p0 * p0 + p1 * p1);
    float ang = atan2f(p0, p1);
    if (ang < 0.f) ang += TWO_PI_F;
    int pidx = (int)(ang / BIN_W_F);
    bool mask = ((fabsf(p0) + fabsf(p1)) != 0.f) && (dist > 0.005f);
    if (mask && pidx >= 0 && pidx < P_) {
      atomicAdd(&whc[w][pidx], 1.f);
      atomicAdd(&whd[w][pidx], dist);
      atomicAdd(&wha[w][pidx], ang);
    }
  }
  __syncthreads();  // B6: layer3 partials + histogram done

  if (tid < 2 * 64) {
    int r = tid >> 6, j = tid & 63;
    float sum = b3[j];
#pragma unroll
    for (int s = 0; s < 32; ++s) sum += spool[(s * 2 + r) * 64 + j];
    f3s[r][j] = fmaxf(sum, 0.f);
  }
  if (tid >= 128 && tid < 144) {  // combine per-wave hist -> per-row
    int i = tid - 128;
    int r = i >> 3, p = i & 7;
    float c = 0.f, d = 0.f, a = 0.f;
#pragma unroll
    for (int w = 0; w < 4; ++w) {
      c += whc[r * 4 + w][p];
      d += whd[r * 4 + w][p];
      a += wha[r * 4 + w][p];
    }
    cnt[r][p] = c;
    dsum[r][p] = d;
    asum[r][p] = a;
  }
  __syncthreads();  // B7: f3s + combined hist ready

  // ---- output: 2 rows x 1024 floats = 512 float4, 1 per thread ----
  {
    int r = tid >> 8, i4 = tid & 255;
    int t = r ? t1 : t0;
    int p = i4 >> 5;
    int c0 = (i4 & 31) * 4;
    float nn = cnt[r][p] + EPS_F;
    float4 v;
    if (c0 < 64) {
      float sc = cnt[r][p] / nn;
      v = make_float4(f3s[r][c0 + 0] * sc, f3s[r][c0 + 1] * sc,
                      f3s[r][c0 + 2] * sc, f3s[r][c0 + 3] * sc);
    } else {
      int jj = c0 - 64;
      float dm = dsum[r][p] / nn;
      float am = asum[r][p] / nn;
      v.x = fmaxf(fmaf(dm, Wce[jj + 0], fmaf(am, Wce[64 + jj + 0], bce[jj + 0])), 0.f);
      v.y = fmaxf(fmaf(dm, Wce[jj + 1], fmaf(am, Wce[64 + jj + 1], bce[jj + 1])), 0.f);
      v.z = fmaxf(fmaf(dm, Wce[jj + 2], fmaf(am, Wce[64 + jj + 2], bce[jj + 2])), 0.f);
      v.w = fmaxf(fmaf(dm, Wce[jj + 3], fmaf(am, Wce[64 + jj + 3], bce[jj + 3])), 0.f);
    }
    *(float4*)(out + ((size_t)b * T_S_ + t) * 1024 + 4 * i4) = v;
  }
}

// ---------------------------------------------------------------------------
extern "C" void kernel_launch(void* const* d_in, const int* in_sizes, int n_in,
                              void* d_out, int out_size, void* d_ws,
                              size_t ws_size, hipStream_t stream) {
  const float* x_ego = (const float*)d_in[0];   // (32,50,2)
  const float* x_nei = (const float*)d_in[1];   // (32,256,50,2)
  const float* f_ego = (const float*)d_in[2];   // (32,25,128)
  const float* f_nei = (const float*)d_in[3];   // (32,256,25,128)
  const float* W1 = (const float*)d_in[4];      // (128,256)
  const float* b1 = (const float*)d_in[5];
  const float* W2 = (const float*)d_in[6];      // (256,256)
  const float* b2 = (const float*)d_in[7];
  const float* W3 = (const float*)d_in[8];      // (256,64)
  const float* b3 = (const float*)d_in[9];
  const float* Wce = (const float*)d_in[10];    // (2,64)
  const float* bce = (const float*)d_in[11];
  float* out = (float*)d_out;                   // (32,25,8,128)

  fused<<<B_ * TG_, 512, 0, stream>>>(f_ego, f_nei, W1, b1, W2, b2, W3, b3,
                                      x_ego, x_nei, Wce, bce, out);
}